// Round 3
// baseline (1440.383 us; speedup 1.0000x reference)
//
#include <hip/hip_runtime.h>
#include <hip/hip_bf16.h>

#define CL 2
#define CB 4
#define CT 1024
#define CD 256
#define CH 4
#define CM 1024
#define CHD (CH * CD)      // 1024
#define NROW (CB * CT)     // 4096

typedef unsigned short ushort_t;

__device__ __forceinline__ float bf2f(unsigned short u) {
    return __uint_as_float(((unsigned int)u) << 16);
}
__device__ __forceinline__ unsigned short f2bf(float f) {
    unsigned int x = __float_as_uint(f);
    return (unsigned short)((x + 0x7fffu + ((x >> 16) & 1u)) >> 16);
}
__device__ __forceinline__ float4 bf4u(ushort4 u) {
    return make_float4(bf2f(u.x), bf2f(u.y), bf2f(u.z), bf2f(u.w));
}

// Input-dtype detection: read `w` as bf16; fp32-underlying data decodes low
// mantissa halfwords to huge/NaN ~21% of the time, true bf16 never does.
// flag=1 -> inputs bf16; flag=0 -> inputs fp32.
__global__ __launch_bounds__(256) void detect_kernel(
    const ushort_t* __restrict__ w, int n, int* __restrict__ flag)
{
    __shared__ int red[256];
    int c = 0;
    for (int i = threadIdx.x; i < n; i += 256) {
        float v = bf2f(w[i]);
        if (!(fabsf(v) <= 1e6f)) c++;
    }
    red[threadIdx.x] = c;
    __syncthreads();
    for (int s = 128; s > 0; s >>= 1) {
        if (threadIdx.x < s) red[threadIdx.x] += red[threadIdx.x + s];
        __syncthreads();
    }
    if (threadIdx.x == 0) flag[0] = (red[0] < 16) ? 1 : 0;
}

// Generic tiled GEMM: C[z] = relu?(alpha * (A[z] @ B[z*sB2 + boff] + bias[bioff..]))
// A: [MxK] row-major, ABF 0=f32 1=bf16 (ws, static). B: BT=0 [KxN], BT=1 [NxK];
// BMODE 0=f32, 1=bf16, 2=dtype per runtime flag (d_in weights). C: CBF 0/1.
// boff/bioff: ELEMENT offsets applied to B/bias inside the kernel (runtime
// dtype makes host-side byte offsets impossible for BMODE=2 operands).
template <int BT, int ABF, int BMODE, int CBF, int RELU>
__global__ __launch_bounds__(256) void gemm_kernel(
    const void* __restrict__ Ap, const void* __restrict__ Bp,
    const void* __restrict__ bias, void* __restrict__ Cp,
    int K, int lda, int ldb, int ldc,
    long sA2, long sB2, long sC2, long boff, long bioff, float alpha,
    const int* __restrict__ flagp)
{
    const int z = blockIdx.z;
    [[maybe_unused]] const int fbf = flagp ? *flagp : 0;

    __shared__ __align__(16) float As[16][68];
    __shared__ __align__(16) float Bs[16][68];

    const int tid = threadIdx.x;
    const int tx = tid & 15;
    const int ty = tid >> 4;
    const long m0 = (long)blockIdx.y * 64;
    const long n0 = (long)blockIdx.x * 64;

    float acc[4][4] = {};

    const int la_m = tid >> 2;
    const int la_k = (tid & 3) << 2;

    for (int k0 = 0; k0 < K; k0 += 16) {
        {
            const long off = (long)z * sA2 + (m0 + la_m) * (long)lda + (k0 + la_k);
            float4 av;
            if constexpr (ABF)
                av = bf4u(*reinterpret_cast<const ushort4*>((const ushort_t*)Ap + off));
            else
                av = *reinterpret_cast<const float4*>((const float*)Ap + off);
            As[la_k + 0][la_m] = av.x;
            As[la_k + 1][la_m] = av.y;
            As[la_k + 2][la_m] = av.z;
            As[la_k + 3][la_m] = av.w;
        }
        if constexpr (BT) {
            const int lb_n = tid >> 2;
            const int lb_k = (tid & 3) << 2;
            const long off = boff + (long)z * sB2 + (n0 + lb_n) * (long)ldb + (k0 + lb_k);
            float4 bv;
            if constexpr (BMODE == 1)
                bv = bf4u(*reinterpret_cast<const ushort4*>((const ushort_t*)Bp + off));
            else
                bv = *reinterpret_cast<const float4*>((const float*)Bp + off);
            Bs[lb_k + 0][lb_n] = bv.x;
            Bs[lb_k + 1][lb_n] = bv.y;
            Bs[lb_k + 2][lb_n] = bv.z;
            Bs[lb_k + 3][lb_n] = bv.w;
        } else {
            const int lb_n = (tid & 15) << 2;
            const int lb_k = tid >> 4;
            const long off = boff + (long)z * sB2 + (long)(k0 + lb_k) * ldb + (n0 + lb_n);
            float4 bv;
            if constexpr (BMODE == 0)
                bv = *reinterpret_cast<const float4*>((const float*)Bp + off);
            else if constexpr (BMODE == 1)
                bv = bf4u(*reinterpret_cast<const ushort4*>((const ushort_t*)Bp + off));
            else
                bv = fbf ? bf4u(*reinterpret_cast<const ushort4*>((const ushort_t*)Bp + off))
                         : *reinterpret_cast<const float4*>((const float*)Bp + off);
            Bs[lb_k][lb_n + 0] = bv.x;
            Bs[lb_k][lb_n + 1] = bv.y;
            Bs[lb_k][lb_n + 2] = bv.z;
            Bs[lb_k][lb_n + 3] = bv.w;
        }
        __syncthreads();
#pragma unroll
        for (int kk = 0; kk < 16; ++kk) {
            float4 a = *reinterpret_cast<const float4*>(&As[kk][ty << 2]);
            float4 b = *reinterpret_cast<const float4*>(&Bs[kk][tx << 2]);
            float ar[4] = {a.x, a.y, a.z, a.w};
            float br[4] = {b.x, b.y, b.z, b.w};
#pragma unroll
            for (int i = 0; i < 4; ++i)
#pragma unroll
                for (int j = 0; j < 4; ++j)
                    acc[i][j] = fmaf(ar[i], br[j], acc[i][j]);
        }
        __syncthreads();
    }

#pragma unroll
    for (int i = 0; i < 4; ++i) {
        const long m = m0 + (ty << 2) + i;
        const long n = n0 + (tx << 2);
        float v[4];
#pragma unroll
        for (int j = 0; j < 4; ++j) {
            v[j] = acc[i][j];
            if (bias)
                v[j] += fbf ? bf2f(((const ushort_t*)bias)[bioff + n + j])
                            : ((const float*)bias)[bioff + n + j];
            v[j] *= alpha;
            if (RELU) v[j] = fmaxf(v[j], 0.f);
        }
        const long coff = (long)z * sC2 + m * (long)ldc + n;
        if constexpr (CBF) {
            ushort4 u;
            u.x = f2bf(v[0]); u.y = f2bf(v[1]); u.z = f2bf(v[2]); u.w = f2bf(v[3]);
            *reinterpret_cast<ushort4*>((ushort_t*)Cp + coff) = u;
        } else {
            float4 f;
            f.x = v[0]; f.y = v[1]; f.z = v[2]; f.w = v[3];
            *reinterpret_cast<float4*>((float*)Cp + coff) = f;
        }
    }
}

__global__ __launch_bounds__(256) void softmax_kernel(float* __restrict__ S)
{
    const long row = blockIdx.x;
    float* p = S + row * (long)CT;
    const int t = threadIdx.x;

    float4 v = *reinterpret_cast<const float4*>(p + (t << 2));
    __shared__ float red[256];

    float mx = fmaxf(fmaxf(v.x, v.y), fmaxf(v.z, v.w));
    red[t] = mx;
    __syncthreads();
    for (int s = 128; s > 0; s >>= 1) {
        if (t < s) red[t] = fmaxf(red[t], red[t + s]);
        __syncthreads();
    }
    mx = red[0];
    __syncthreads();

    v.x = __expf(v.x - mx);
    v.y = __expf(v.y - mx);
    v.z = __expf(v.z - mx);
    v.w = __expf(v.w - mx);
    red[t] = v.x + v.y + v.z + v.w;
    __syncthreads();
    for (int s = 128; s > 0; s >>= 1) {
        if (t < s) red[t] += red[t + s];
        __syncthreads();
    }
    const float inv = 1.0f / red[0];

    v.x *= inv; v.y *= inv; v.z *= inv; v.w *= inv;
    *reinterpret_cast<float4*>(p + (t << 2)) = v;
}

// Residual + LayerNorm. XBF = residual dtype. sc/bi from d_in (+loff elems).
template <int XBF>
__global__ __launch_bounds__(256) void ln_kernel(
    const void* __restrict__ o, const void* __restrict__ res,
    const void* __restrict__ sc, const void* __restrict__ bi,
    void* __restrict__ out, long loff, const int* __restrict__ flagp)
{
    const int fbf = *flagp;
    const long row = blockIdx.x;
    const int t = threadIdx.x;
    float x;
    if constexpr (XBF)
        x = bf2f(((const ushort_t*)o)[row * CD + t]) +
            bf2f(((const ushort_t*)res)[row * CD + t]);
    else
        x = ((const float*)o)[row * CD + t] + ((const float*)res)[row * CD + t];

    __shared__ float r1[256];
    __shared__ float r2[256];
    r1[t] = x;
    r2[t] = x * x;
    __syncthreads();
    for (int s = 128; s > 0; s >>= 1) {
        if (t < s) { r1[t] += r1[t + s]; r2[t] += r2[t + s]; }
        __syncthreads();
    }
    const float mean = r1[0] * (1.0f / CD);
    const float var = r2[0] * (1.0f / CD) - mean * mean;
    const float rstd = rsqrtf(var + 1e-5f);
    const float s_v = fbf ? bf2f(((const ushort_t*)sc)[loff + t]) : ((const float*)sc)[loff + t];
    const float b_v = fbf ? bf2f(((const ushort_t*)bi)[loff + t]) : ((const float*)bi)[loff + t];
    const float y = (x - mean) * rstd * s_v + b_v;
    if constexpr (XBF)
        ((ushort_t*)out)[row * CD + t] = f2bf(y);
    else
        ((float*)out)[row * CD + t] = y;
}

template <int XBF>
__global__ __launch_bounds__(256) void in_convert(
    const void* __restrict__ in, void* __restrict__ x,
    const int* __restrict__ flagp)
{
    const int fbf = *flagp;
    const long i = ((long)blockIdx.x * 256 + threadIdx.x) << 2;
    float4 f = fbf ? bf4u(*reinterpret_cast<const ushort4*>((const ushort_t*)in + i))
                   : *reinterpret_cast<const float4*>((const float*)in + i);
    if constexpr (XBF) {
        ushort4 u;
        u.x = f2bf(f.x); u.y = f2bf(f.y); u.z = f2bf(f.z); u.w = f2bf(f.w);
        *reinterpret_cast<ushort4*>((ushort_t*)x + i) = u;
    } else {
        *reinterpret_cast<float4*>((float*)x + i) = f;
    }
}

template <int XBF>
__global__ __launch_bounds__(256) void out_write(
    const void* __restrict__ x, void* __restrict__ out,
    const int* __restrict__ flagp)
{
    const int fbf = *flagp;
    const long i = ((long)blockIdx.x * 256 + threadIdx.x) << 2;
    float4 f;
    if constexpr (XBF)
        f = bf4u(*reinterpret_cast<const ushort4*>((const ushort_t*)x + i));
    else
        f = *reinterpret_cast<const float4*>((const float*)x + i);
    if (fbf) {
        ushort4 u;
        u.x = f2bf(f.x); u.y = f2bf(f.y); u.z = f2bf(f.z); u.w = f2bf(f.w);
        *reinterpret_cast<ushort4*>((ushort_t*)out + i) = u;
    } else {
        *reinterpret_cast<float4*>((float*)out + i) = f;
    }
}

extern "C" void kernel_launch(void* const* d_in, const int* in_sizes, int n_in,
                              void* d_out, int out_size, void* d_ws, size_t ws_size,
                              hipStream_t stream)
{
    const void* queries = d_in[0];
    const void* Wq = d_in[1];  const void* bq = d_in[2];
    const void* Wk = d_in[3];  const void* bk = d_in[4];
    const void* Wv = d_in[5];  const void* bv = d_in[6];
    const void* Wo = d_in[7];  const void* bo = d_in[8];
    const void* ln1s = d_in[9];  const void* ln1b = d_in[10];
    const void* W1 = d_in[11]; const void* b1 = d_in[12];
    const void* W2 = d_in[13]; const void* b2 = d_in[14];
    const void* ln2s = d_in[15]; const void* ln2b = d_in[16];

    const size_t MB = 1ull << 20;
    char* base = (char*)d_ws;
    int* flagp = (int*)base;                 // 256 B for flag
    char* p = base + 256;

    // mode 2: xa,xb f32 (8MB) + qkv bf16 (24MB) + S f32 16MB = 48MB+256
    // mode 1: xa,xb f32 (8MB) + qkv bf16 (24MB); S aliases xb = 32MB+256
    // mode 0: xa,xb bf16 (4MB) + qkv bf16 (24MB) + S 1MB      = 29MB+256
    const int mode = (ws_size >= 256 + 48 * MB) ? 2
                   : (ws_size >= 256 + 32 * MB) ? 1 : 0;
    const int xbf = (mode == 0) ? 1 : 0;

    char* xa_p = p;              p += (xbf ? 2 : 4) * MB;
    char* xb_p = p;              p += (xbf ? 2 : 4) * MB;
    ushort_t* q  = (ushort_t*)p; p += 8 * MB;
    ushort_t* kk = (ushort_t*)p; p += 8 * MB;
    ushort_t* vv = (ushort_t*)p; p += 8 * MB;
    float* S = (mode == 1) ? (float*)xb_p : (float*)p;

    const long WQKV = (long)CD * CHD;
    const long WOUT = (long)CHD * CD;
    const long nrow_cd = (long)NROW * CD;

    detect_kernel<<<1, 256, 0, stream>>>((const ushort_t*)Wq, 65536, flagp);

    if (!xbf) in_convert<0><<<nrow_cd / 1024, 256, 0, stream>>>(queries, xa_p, flagp);
    else      in_convert<1><<<nrow_cd / 1024, 256, 0, stream>>>(queries, xa_p, flagp);

    for (int l = 0; l < CL; ++l) {
        const long wq_off = (long)l * WQKV;
        const long wo_off = (long)l * WOUT;
        const long bh_off = (long)l * CHD;
        const long bd_off = (long)l * CD;

        if (!xbf) {
            gemm_kernel<0, 0, 2, 1, 0><<<dim3(16, 64, 1), 256, 0, stream>>>(
                xa_p, Wq, bq, q, CD, CD, CHD, CHD, 0, 0, 0, wq_off, bh_off, 0.0625f, flagp);
            gemm_kernel<0, 0, 2, 1, 0><<<dim3(16, 64, 1), 256, 0, stream>>>(
                xa_p, Wk, bk, kk, CD, CD, CHD, CHD, 0, 0, 0, wq_off, bh_off, 1.0f, flagp);
            gemm_kernel<0, 0, 2, 1, 0><<<dim3(16, 64, 1), 256, 0, stream>>>(
                xa_p, Wv, bv, vv, CD, CD, CHD, CHD, 0, 0, 0, wq_off, bh_off, 1.0f, flagp);
        } else {
            gemm_kernel<0, 1, 2, 1, 0><<<dim3(16, 64, 1), 256, 0, stream>>>(
                xa_p, Wq, bq, q, CD, CD, CHD, CHD, 0, 0, 0, wq_off, bh_off, 0.0625f, flagp);
            gemm_kernel<0, 1, 2, 1, 0><<<dim3(16, 64, 1), 256, 0, stream>>>(
                xa_p, Wk, bk, kk, CD, CD, CHD, CHD, 0, 0, 0, wq_off, bh_off, 1.0f, flagp);
            gemm_kernel<0, 1, 2, 1, 0><<<dim3(16, 64, 1), 256, 0, stream>>>(
                xa_p, Wv, bv, vv, CD, CD, CHD, CHD, 0, 0, 0, wq_off, bh_off, 1.0f, flagp);
        }

        if (mode == 2) {
            for (int b = 0; b < CB; ++b) {
                const long qo = (long)b * CT * CHD;
                gemm_kernel<1, 1, 1, 0, 0><<<dim3(16, 16, CH), 256, 0, stream>>>(
                    q + qo, kk + qo, nullptr, S, CD, CHD, CHD, CT,
                    CD, CD, (long)CT * CT, 0, 0, 1.0f, nullptr);
                softmax_kernel<<<CH * CT, 256, 0, stream>>>(S);
                gemm_kernel<0, 0, 1, 1, 0><<<dim3(4, 16, CH), 256, 0, stream>>>(
                    S, vv + qo, nullptr, q + qo, CT, CT, CHD, CHD,
                    (long)CT * CT, CD, CD, 0, 0, 1.0f, nullptr);
            }
        } else if (mode == 1) {
            for (int b = 0; b < CB; ++b)
                for (int h = 0; h < CH; ++h) {
                    const long o = (long)b * CT * CHD + (long)h * CD;
                    gemm_kernel<1, 1, 1, 0, 0><<<dim3(16, 16, 1), 256, 0, stream>>>(
                        q + o, kk + o, nullptr, S, CD, CHD, CHD, CT,
                        0, 0, 0, 0, 0, 1.0f, nullptr);
                    softmax_kernel<<<CT, 256, 0, stream>>>(S);
                    gemm_kernel<0, 0, 1, 1, 0><<<dim3(4, 16, 1), 256, 0, stream>>>(
                        S, vv + o, nullptr, q + o, CT, CT, CHD, CHD,
                        0, 0, 0, 0, 0, 1.0f, nullptr);
                }
        } else {
            for (int b = 0; b < CB; ++b)
                for (int h = 0; h < CH; ++h) {
                    const long ko = (long)b * CT * CHD + (long)h * CD;
                    for (int c = 0; c < 4; ++c) {
                        const long qo = ko + (long)c * 256 * CHD;
                        gemm_kernel<1, 1, 1, 0, 0><<<dim3(16, 4, 1), 256, 0, stream>>>(
                            q + qo, kk + ko, nullptr, S, CD, CHD, CHD, CT,
                            0, 0, 0, 0, 0, 1.0f, nullptr);
                        softmax_kernel<<<256, 256, 0, stream>>>(S);
                        gemm_kernel<0, 0, 1, 1, 0><<<dim3(4, 4, 1), 256, 0, stream>>>(
                            S, vv + ko, nullptr, q + qo, CT, CT, CHD, CHD,
                            0, 0, 0, 0, 0, 1.0f, nullptr);
                    }
                }
        }

        if (!xbf) {
            gemm_kernel<0, 1, 2, 0, 0><<<dim3(4, 64, 1), 256, 0, stream>>>(
                q, Wo, bo, xb_p, CHD, CHD, CD, CD, 0, 0, 0, wo_off, bd_off, 1.0f, flagp);
            ln_kernel<0><<<NROW, 256, 0, stream>>>(xb_p, xa_p, ln1s, ln1b, xb_p, bd_off, flagp);
            gemm_kernel<0, 0, 2, 1, 1><<<dim3(16, 64, 1), 256, 0, stream>>>(
                xb_p, W1, b1, kk, CD, CD, CM, CM, 0, 0, 0, wq_off, bh_off, 1.0f, flagp);
            gemm_kernel<0, 1, 2, 0, 0><<<dim3(4, 64, 1), 256, 0, stream>>>(
                kk, W2, b2, xa_p, CM, CM, CD, CD, 0, 0, 0, wo_off, bd_off, 1.0f, flagp);
            ln_kernel<0><<<NROW, 256, 0, stream>>>(xa_p, xb_p, ln2s, ln2b, xa_p, bd_off, flagp);
        } else {
            gemm_kernel<0, 1, 2, 1, 0><<<dim3(4, 64, 1), 256, 0, stream>>>(
                q, Wo, bo, xb_p, CHD, CHD, CD, CD, 0, 0, 0, wo_off, bd_off, 1.0f, flagp);
            ln_kernel<1><<<NROW, 256, 0, stream>>>(xb_p, xa_p, ln1s, ln1b, xb_p, bd_off, flagp);
            gemm_kernel<0, 1, 2, 1, 1><<<dim3(16, 64, 1), 256, 0, stream>>>(
                xb_p, W1, b1, kk, CD, CD, CM, CM, 0, 0, 0, wq_off, bh_off, 1.0f, flagp);
            gemm_kernel<0, 1, 2, 1, 0><<<dim3(4, 64, 1), 256, 0, stream>>>(
                kk, W2, b2, xa_p, CM, CM, CD, CD, 0, 0, 0, wo_off, bd_off, 1.0f, flagp);
            ln_kernel<1><<<NROW, 256, 0, stream>>>(xa_p, xb_p, ln2s, ln2b, xa_p, bd_off, flagp);
        }
    }

    if (!xbf) out_write<0><<<nrow_cd / 1024, 256, 0, stream>>>(xa_p, d_out, flagp);
    else      out_write<1><<<nrow_cd / 1024, 256, 0, stream>>>(xa_p, d_out, flagp);
}

// Round 4
// 755.781 us; speedup vs baseline: 1.9058x; 1.9058x over previous
//
#include <hip/hip_runtime.h>
#include <hip/hip_bf16.h>

#define CL 2
#define CB 4
#define CT 1024
#define CD 256
#define CH 4
#define CM 1024
#define CHD (CH * CD)      // 1024
#define NROW (CB * CT)     // 4096

typedef unsigned short ushort_t;
typedef __attribute__((ext_vector_type(8))) short short8v;   // 8 bf16 (4 VGPR)
typedef __attribute__((ext_vector_type(4))) float float4v;   // MFMA C/D frag

__device__ __forceinline__ float bf2f(unsigned short u) {
    return __uint_as_float(((unsigned int)u) << 16);
}
__device__ __forceinline__ unsigned short f2bf(float f) {
    unsigned int x = __float_as_uint(f);
    return (unsigned short)((x + 0x7fffu + ((x >> 16) & 1u)) >> 16);
}

// ---------------------------------------------------------------------------
// Input-dtype detection (kept from round 3 — it resolved the dtype question).
// Reads `w` as bf16; fp32-underlying data decodes to huge/NaN ~21% of the
// time, true bf16 never. flag=1 -> inputs bf16; 0 -> fp32.
// ---------------------------------------------------------------------------
__global__ __launch_bounds__(256) void detect_kernel(
    const ushort_t* __restrict__ w, int n, int* __restrict__ flag)
{
    __shared__ int red[256];
    int c = 0;
    for (int i = threadIdx.x; i < n; i += 256) {
        float v = bf2f(w[i]);
        if (!(fabsf(v) <= 1e6f)) c++;
    }
    red[threadIdx.x] = c;
    __syncthreads();
    for (int s = 128; s > 0; s >>= 1) {
        if (threadIdx.x < s) red[threadIdx.x] += red[threadIdx.x + s];
        __syncthreads();
    }
    if (threadIdx.x == 0) flag[0] = (red[0] < 16) ? 1 : 0;
}

// ---------------------------------------------------------------------------
// Weight transpose+convert: in [Z][R][C] (dtype per flag) -> out bf16 [Z][C][R]
// inzs/outzs: per-z strides in ELEMENTS. R,C multiples of 32.
// ---------------------------------------------------------------------------
__global__ __launch_bounds__(256) void tconv_kernel(
    const void* __restrict__ in, ushort_t* __restrict__ out,
    int R, int C, long inzs, long outzs, const int* __restrict__ flagp)
{
    const int fbf = *flagp;
    __shared__ float tile[32][33];
    const long zi = (long)blockIdx.z * inzs;
    const long zo = (long)blockIdx.z * outzs;
    const int r0 = blockIdx.y * 32;
    const int c0 = blockIdx.x * 32;
    const int tx = threadIdx.x & 31;
    const int ty = threadIdx.x >> 5;       // 0..7
#pragma unroll
    for (int i = 0; i < 32; i += 8) {
        const long idx = zi + (long)(r0 + ty + i) * C + c0 + tx;
        tile[ty + i][tx] = fbf ? bf2f(((const ushort_t*)in)[idx])
                               : ((const float*)in)[idx];
    }
    __syncthreads();
#pragma unroll
    for (int i = 0; i < 32; i += 8)
        out[zo + (long)(c0 + ty + i) * R + r0 + tx] = f2bf(tile[tx][ty + i]);
}

// ---------------------------------------------------------------------------
// MFMA GEMM: C[z] = relu?(alpha * A[z]B[z]^T + bias)
//   A: bf16 [M x K] row-major (lda), offset z*sA2
//   B: bf16 [N x K] row-major (ldb), offset z*sB2  ("B^T input" form)
//   C: bf16; CMODE 1 = row-major [M x N] (ldc), CMODE 2 = transposed write
//            C[n*ldc + m] (used to produce V^T directly)
//   biasA/biasB from d_in (dtype per flag); biasB serves cols >= 1024
//   (QKV merge); boff = per-layer ELEMENT offset for both.
// Tile 128x128, BK=32, 256 threads = 4 waves, each wave 64x64 via 4x4
// mfma_f32_16x16x32_bf16. M,N mult of 128; K mult of 32. fp32 accumulate.
// Verified layouts (m89/m91/m92): A/B frag [row=lane&15][k=quad*8+j];
// C/D row=quad*4+reg, col=lane&15.
// ---------------------------------------------------------------------------
template <int CMODE, int RELU>
__global__ __launch_bounds__(256) void mgemm(
    const ushort_t* __restrict__ A, const ushort_t* __restrict__ B,
    const void* __restrict__ biasA, const void* __restrict__ biasB,
    ushort_t* __restrict__ C, int K, int lda, int ldb, int ldc,
    long sA2, long sB2, long sC2, long boff, float alpha,
    const int* __restrict__ flagp)
{
    const int z = blockIdx.z;
    const long m0 = (long)blockIdx.y * 128;
    const long n0 = (long)blockIdx.x * 128;
    A += z * sA2;
    B += z * sB2;

    __shared__ __align__(16) ushort_t As[128 * 32];
    __shared__ __align__(16) ushort_t Bs[128 * 32];

    const int tid = threadIdx.x;
    const int wave = tid >> 6;
    const int lane = tid & 63;
    const int quad = lane >> 4;        // 0..3
    const int lrow = lane & 15;        // 0..15
    const int wm = (wave >> 1) * 64;   // wave's m-quadrant
    const int wn = (wave & 1) * 64;    // wave's n-quadrant

    float4v acc[4][4];
#pragma unroll
    for (int i = 0; i < 4; ++i)
#pragma unroll
        for (int j = 0; j < 4; ++j)
            acc[i][j] = (float4v){0.f, 0.f, 0.f, 0.f};

    for (int k0 = 0; k0 < K; k0 += 32) {
        __syncthreads();
        // Stage A (128x32) and B^T (128x32) tiles; 16B per thread per pass.
#pragma unroll
        for (int p = 0; p < 2; ++p) {
            const int c = p * 256 + tid;          // chunk 0..511
            const int row = c >> 2;               // 0..127
            const int kk = (c & 3) << 3;          // 0,8,16,24
            *reinterpret_cast<short8v*>(&As[c << 3]) =
                *reinterpret_cast<const short8v*>(&A[(m0 + row) * (long)lda + k0 + kk]);
            *reinterpret_cast<short8v*>(&Bs[c << 3]) =
                *reinterpret_cast<const short8v*>(&B[(n0 + row) * (long)ldb + k0 + kk]);
        }
        __syncthreads();

        short8v af[4], bfv[4];
#pragma unroll
        for (int i = 0; i < 4; ++i) {
            af[i]  = *reinterpret_cast<const short8v*>(&As[(wm + i * 16 + lrow) * 32 + quad * 8]);
            bfv[i] = *reinterpret_cast<const short8v*>(&Bs[(wn + i * 16 + lrow) * 32 + quad * 8]);
        }
#pragma unroll
        for (int mi = 0; mi < 4; ++mi)
#pragma unroll
            for (int ni = 0; ni < 4; ++ni)
                acc[mi][ni] = __builtin_amdgcn_mfma_f32_16x16x32_bf16(
                    af[mi], bfv[ni], acc[mi][ni], 0, 0, 0);
    }

    const int fbf = flagp ? *flagp : 0;
#pragma unroll
    for (int mi = 0; mi < 4; ++mi) {
#pragma unroll
        for (int ni = 0; ni < 4; ++ni) {
            const long col = n0 + wn + ni * 16 + lrow;
            const long row0 = m0 + wm + mi * 16 + quad * 4;
            float bv = 0.f;
            if (biasA) {
                const void* bp = biasA;
                long bn = col;
                if (biasB && col >= 1024) { bp = biasB; bn = col - 1024; }
                bv = fbf ? bf2f(((const ushort_t*)bp)[boff + bn])
                         : ((const float*)bp)[boff + bn];
            }
            if constexpr (CMODE == 1) {
#pragma unroll
                for (int r = 0; r < 4; ++r) {
                    float v = acc[mi][ni][r] * alpha + bv;
                    if (RELU) v = fmaxf(v, 0.f);
                    C[(long)z * sC2 + (row0 + r) * (long)ldc + col] = f2bf(v);
                }
            } else {
                ushort4 u;
                float v0 = acc[mi][ni][0] * alpha + bv;
                float v1 = acc[mi][ni][1] * alpha + bv;
                float v2 = acc[mi][ni][2] * alpha + bv;
                float v3 = acc[mi][ni][3] * alpha + bv;
                if (RELU) {
                    v0 = fmaxf(v0, 0.f); v1 = fmaxf(v1, 0.f);
                    v2 = fmaxf(v2, 0.f); v3 = fmaxf(v3, 0.f);
                }
                u.x = f2bf(v0); u.y = f2bf(v1); u.z = f2bf(v2); u.w = f2bf(v3);
                *reinterpret_cast<ushort4*>(&C[(long)z * sC2 + col * (long)ldc + row0]) = u;
            }
        }
    }
}

// ---------------------------------------------------------------------------
// Row softmax over 1024 bf16 in place. One block per row, 4 elems/thread.
// ---------------------------------------------------------------------------
__global__ __launch_bounds__(256) void softmax_bf(ushort_t* __restrict__ S)
{
    ushort_t* p = S + (long)blockIdx.x * CT;
    const int t = threadIdx.x;
    ushort4 u = reinterpret_cast<const ushort4*>(p)[t];
    float4 v = make_float4(bf2f(u.x), bf2f(u.y), bf2f(u.z), bf2f(u.w));

    __shared__ float red[256];
    float mx = fmaxf(fmaxf(v.x, v.y), fmaxf(v.z, v.w));
    red[t] = mx;
    __syncthreads();
    for (int s = 128; s > 0; s >>= 1) {
        if (t < s) red[t] = fmaxf(red[t], red[t + s]);
        __syncthreads();
    }
    mx = red[0];
    __syncthreads();

    v.x = __expf(v.x - mx); v.y = __expf(v.y - mx);
    v.z = __expf(v.z - mx); v.w = __expf(v.w - mx);
    red[t] = v.x + v.y + v.z + v.w;
    __syncthreads();
    for (int s = 128; s > 0; s >>= 1) {
        if (t < s) red[t] += red[t + s];
        __syncthreads();
    }
    const float inv = 1.0f / red[0];

    u.x = f2bf(v.x * inv); u.y = f2bf(v.y * inv);
    u.z = f2bf(v.z * inv); u.w = f2bf(v.w * inv);
    reinterpret_cast<ushort4*>(p)[t] = u;
}

// ---------------------------------------------------------------------------
// Residual + LayerNorm, bf16 stream, fp32 stats. sc/bi from d_in (+loff).
// out may alias o or res (read-before-write per row).
// ---------------------------------------------------------------------------
__global__ __launch_bounds__(256) void ln_bf(
    const ushort_t* __restrict__ o, const ushort_t* __restrict__ res,
    const void* __restrict__ sc, const void* __restrict__ bi,
    ushort_t* __restrict__ out, long loff, const int* __restrict__ flagp)
{
    const int fbf = *flagp;
    const long row = (long)blockIdx.x * CD;
    const int t = threadIdx.x;
    const float x = bf2f(o[row + t]) + bf2f(res[row + t]);

    __shared__ float r1[256];
    __shared__ float r2[256];
    r1[t] = x;
    r2[t] = x * x;
    __syncthreads();
    for (int s = 128; s > 0; s >>= 1) {
        if (t < s) { r1[t] += r1[t + s]; r2[t] += r2[t + s]; }
        __syncthreads();
    }
    const float mean = r1[0] * (1.0f / CD);
    const float var = r2[0] * (1.0f / CD) - mean * mean;
    const float rstd = rsqrtf(var + 1e-5f);
    const float s_v = fbf ? bf2f(((const ushort_t*)sc)[loff + t]) : ((const float*)sc)[loff + t];
    const float b_v = fbf ? bf2f(((const ushort_t*)bi)[loff + t]) : ((const float*)bi)[loff + t];
    out[row + t] = f2bf((x - mean) * rstd * s_v + b_v);
}

// queries (dtype per flag) -> bf16 stream
__global__ __launch_bounds__(256) void in_convert(
    const void* __restrict__ in, ushort_t* __restrict__ x,
    const int* __restrict__ flagp)
{
    const int fbf = *flagp;
    const long i = ((long)blockIdx.x * 256 + threadIdx.x) << 2;
    if (fbf) {
        *reinterpret_cast<ushort4*>(x + i) =
            *reinterpret_cast<const ushort4*>((const ushort_t*)in + i);
    } else {
        float4 f = *reinterpret_cast<const float4*>((const float*)in + i);
        ushort4 u;
        u.x = f2bf(f.x); u.y = f2bf(f.y); u.z = f2bf(f.z); u.w = f2bf(f.w);
        *reinterpret_cast<ushort4*>(x + i) = u;
    }
}

// bf16 stream -> d_out (dtype per flag)
__global__ __launch_bounds__(256) void out_write(
    const ushort_t* __restrict__ x, void* __restrict__ out,
    const int* __restrict__ flagp)
{
    const int fbf = *flagp;
    const long i = ((long)blockIdx.x * 256 + threadIdx.x) << 2;
    ushort4 u = *reinterpret_cast<const ushort4*>(x + i);
    if (fbf) {
        *reinterpret_cast<ushort4*>((ushort_t*)out + i) = u;
    } else {
        float4 f = make_float4(bf2f(u.x), bf2f(u.y), bf2f(u.z), bf2f(u.w));
        *reinterpret_cast<float4*>((float*)out + i) = f;
    }
}

// ---------------------------------------------------------------------------
// Orchestration. ws >= 48MB+256 established (round-3 ran mode 2: 2.15GF
// dispatches matched VALUBusy). Layout below: 42.3 MB.
// ---------------------------------------------------------------------------
extern "C" void kernel_launch(void* const* d_in, const int* in_sizes, int n_in,
                              void* d_out, int out_size, void* d_ws, size_t ws_size,
                              hipStream_t stream)
{
    const void* queries = d_in[0];
    const void* Wq = d_in[1];  const void* bq = d_in[2];
    const void* Wk = d_in[3];  const void* bk = d_in[4];
    const void* Wv = d_in[5];  const void* bv = d_in[6];
    const void* Wo = d_in[7];  const void* bo = d_in[8];
    const void* ln1s = d_in[9];  const void* ln1b = d_in[10];
    const void* W1 = d_in[11]; const void* b1 = d_in[12];
    const void* W2 = d_in[13]; const void* b2 = d_in[14];
    const void* ln2s = d_in[15]; const void* ln2b = d_in[16];

    char* p = (char*)d_ws;
    int* flagp = (int*)p;            p += 256;
    ushort_t* wqkT = (ushort_t*)p;   p += (long)CL * 2048 * 256 * 2;   // 2 MB
    ushort_t* wvT  = (ushort_t*)p;   p += (long)CL * 1024 * 256 * 2;   // 1 MB
    ushort_t* woT  = (ushort_t*)p;   p += (long)CL * 256 * 1024 * 2;   // 1 MB
    ushort_t* w1T  = (ushort_t*)p;   p += (long)CL * 1024 * 256 * 2;   // 1 MB
    ushort_t* w2T  = (ushort_t*)p;   p += (long)CL * 256 * 1024 * 2;   // 1 MB
    ushort_t* xa   = (ushort_t*)p;   p += (long)NROW * CD * 2;         // 2 MB
    ushort_t* xb   = (ushort_t*)p;   p += (long)NROW * CD * 2;         // 2 MB
    ushort_t* qk   = (ushort_t*)p;   p += (long)NROW * 2048 * 2;       // 16 MB
    ushort_t* vT   = (ushort_t*)p;   p += (long)CB * CH * 256 * 1024 * 2; // 8 MB
    ushort_t* S    = (ushort_t*)p;   p += (long)CH * CT * CT * 2;      // 8 MB
    ushort_t* h    = vT;  // MLP hidden reuses vT (dead after attention)

    // --- pre-pass: dtype flag, weight transposes (all layers), input convert
    detect_kernel<<<1, 256, 0, stream>>>((const ushort_t*)Wq, 65536, flagp);

    // Wq/Wk -> wqkT[l] = [2048][256] (rows 0..1023 = WqT, 1024.. = WkT)
    tconv_kernel<<<dim3(32, 8, CL), 256, 0, stream>>>(
        Wq, wqkT, 256, 1024, 256 * 1024, 2048 * 256, flagp);
    tconv_kernel<<<dim3(32, 8, CL), 256, 0, stream>>>(
        Wk, wqkT + 1024 * 256, 256, 1024, 256 * 1024, 2048 * 256, flagp);
    tconv_kernel<<<dim3(32, 8, CL), 256, 0, stream>>>(
        Wv, wvT, 256, 1024, 256 * 1024, 1024 * 256, flagp);
    tconv_kernel<<<dim3(8, 32, CL), 256, 0, stream>>>(
        Wo, woT, 1024, 256, 1024 * 256, 256 * 1024, flagp);
    tconv_kernel<<<dim3(32, 8, CL), 256, 0, stream>>>(
        W1, w1T, 256, 1024, 256 * 1024, 1024 * 256, flagp);
    tconv_kernel<<<dim3(8, 32, CL), 256, 0, stream>>>(
        W2, w2T, 1024, 256, 1024 * 256, 256 * 1024, flagp);

    in_convert<<<(NROW * CD) / 1024, 256, 0, stream>>>(queries, xa, flagp);

    for (int l = 0; l < CL; ++l) {
        // 1) Q|K projection: xa [4096,256] @ wqkT[l]^T -> qk [4096,2048]
        mgemm<1, 0><<<dim3(16, 32, 1), 256, 0, stream>>>(
            xa, wqkT + (long)l * 2048 * 256, bq, bk, qk,
            256, 256, 256, 2048, 0, 0, 0, (long)l * 1024, 1.0f, flagp);
        // 2) V projection with transposed write: per-b z, vT[b][h][d][t]
        mgemm<2, 0><<<dim3(8, 8, CB), 256, 0, stream>>>(
            xa, wvT + (long)l * 1024 * 256, bv, nullptr, vT,
            256, 256, 256, 1024, (long)CT * 256, 0, (long)CT * CT,
            (long)l * 1024, 1.0f, flagp);

        // 3) attention per batch element, heads batched via z
        for (int b = 0; b < CB; ++b) {
            const long qb = (long)b * CT * 2048;
            // S[h] = (q_bh @ k_bh^T) / 16   (bf16 out)
            mgemm<1, 0><<<dim3(8, 8, CH), 256, 0, stream>>>(
                qk + qb, qk + qb + 1024, nullptr, nullptr, S,
                256, 2048, 2048, 1024, 256, 256, (long)CT * CT,
                0, 0.0625f, nullptr);
            softmax_bf<<<CH * CT, 256, 0, stream>>>(S);
            // ao_bh = P @ v_bh   (B = vT slice, [256][1024]); writes q-slice
            mgemm<1, 0><<<dim3(2, 8, CH), 256, 0, stream>>>(
                S, vT + (long)b * CH * 256 * 1024, nullptr, nullptr, qk + qb,
                1024, 1024, 1024, 2048, (long)CT * CT, 256 * 1024, 256,
                0, 1.0f, nullptr);
        }

        // 4) O projection: ao (qk cols 0..1023) @ woT[l]^T + bo -> xb
        mgemm<1, 0><<<dim3(2, 32, 1), 256, 0, stream>>>(
            qk, woT + (long)l * 256 * 1024, bo, nullptr, xb,
            1024, 2048, 1024, 256, 0, 0, 0, (long)l * 256, 1.0f, flagp);
        // 5) xa = LN(xb + xa)
        ln_bf<<<NROW, 256, 0, stream>>>(xb, xa, ln1s, ln1b, xa,
                                        (long)l * 256, flagp);
        // 6) h = relu(xa @ w1T[l]^T + b1)
        mgemm<1, 1><<<dim3(8, 32, 1), 256, 0, stream>>>(
            xa, w1T + (long)l * 1024 * 256, b1, nullptr, h,
            256, 256, 256, 1024, 0, 0, 0, (long)l * 1024, 1.0f, flagp);
        // 7) m = h @ w2T[l]^T + b2 -> xb
        mgemm<1, 0><<<dim3(2, 32, 1), 256, 0, stream>>>(
            h, w2T + (long)l * 256 * 1024, b2, nullptr, xb,
            1024, 1024, 1024, 256, 0, 0, 0, (long)l * 256, 1.0f, flagp);
        // 8) xa = LN(xb + xa)
        ln_bf<<<NROW, 256, 0, stream>>>(xb, xa, ln2s, ln2b, xa,
                                        (long)l * 256, flagp);
    }

    out_write<<<(NROW * CD) / 1024, 256, 0, stream>>>(xa, d_out, flagp);
}

// Round 5
// 472.526 us; speedup vs baseline: 3.0483x; 1.5994x over previous
//
#include <hip/hip_runtime.h>
#include <hip/hip_bf16.h>

#define CL 2
#define CB 4
#define CT 1024
#define CD 256
#define CH 4
#define CM 1024
#define CHD (CH * CD)      // 1024
#define NROW (CB * CT)     // 4096

typedef unsigned short ushort_t;
typedef __attribute__((ext_vector_type(8))) short short8v;   // 8 bf16 (4 VGPR)
typedef __attribute__((ext_vector_type(4))) float float4v;   // MFMA C/D frag

__device__ __forceinline__ float bf2f(unsigned short u) {
    return __uint_as_float(((unsigned int)u) << 16);
}
__device__ __forceinline__ unsigned short f2bf(float f) {
    unsigned int x = __float_as_uint(f);
    return (unsigned short)((x + 0x7fffu + ((x >> 16) & 1u)) >> 16);
}

// ---------------------------------------------------------------------------
// Input-dtype detection. Round-4 lesson: 65536 elems @ 1 block = 50 us (top
// dispatch!). 2048 elems suffices: fp32-underlying -> ~430 expected anomalies,
// bf16 -> 0. flag=1 -> inputs bf16; 0 -> fp32.
// ---------------------------------------------------------------------------
__global__ __launch_bounds__(256) void detect_kernel(
    const ushort_t* __restrict__ w, int n, int* __restrict__ flag)
{
    __shared__ int red[256];
    int c = 0;
    for (int i = threadIdx.x; i < n; i += 256) {
        float v = bf2f(w[i]);
        if (!(fabsf(v) <= 1e6f)) c++;
    }
    red[threadIdx.x] = c;
    __syncthreads();
    for (int s = 128; s > 0; s >>= 1) {
        if (threadIdx.x < s) red[threadIdx.x] += red[threadIdx.x + s];
        __syncthreads();
    }
    if (threadIdx.x == 0) flag[0] = (red[0] < 8) ? 1 : 0;
}

// ---------------------------------------------------------------------------
// Weight transpose+convert: in [Z][R][C] (dtype per flag) -> out bf16 [Z][C][R]
// ---------------------------------------------------------------------------
__global__ __launch_bounds__(256) void tconv_kernel(
    const void* __restrict__ in, ushort_t* __restrict__ out,
    int R, int C, long inzs, long outzs, const int* __restrict__ flagp)
{
    const int fbf = *flagp;
    __shared__ float tile[32][33];
    const long zi = (long)blockIdx.z * inzs;
    const long zo = (long)blockIdx.z * outzs;
    const int r0 = blockIdx.y * 32;
    const int c0 = blockIdx.x * 32;
    const int tx = threadIdx.x & 31;
    const int ty = threadIdx.x >> 5;
#pragma unroll
    for (int i = 0; i < 32; i += 8) {
        const long idx = zi + (long)(r0 + ty + i) * C + c0 + tx;
        tile[ty + i][tx] = fbf ? bf2f(((const ushort_t*)in)[idx])
                               : ((const float*)in)[idx];
    }
    __syncthreads();
#pragma unroll
    for (int i = 0; i < 32; i += 8)
        out[zo + (long)(c0 + ty + i) * R + r0 + tx] = f2bf(tile[tx][ty + i]);
}

// ---------------------------------------------------------------------------
// MFMA GEMM (verified round 4): C[z] = relu?(alpha * A[z]B[z]^T + bias)
// A bf16 [MxK] (lda); B bf16 [NxK] (ldb); C bf16: CMODE 1 row-major,
// CMODE 2 transposed write C[n*ldc+m]. Semantics established:
// D[m][n] = sum_k Afrag[m=lane&15][k=quad*8+j] * Bfrag[n=lane&15][k],
// C/D row=quad*4+reg, col=lane&15.
// ---------------------------------------------------------------------------
template <int CMODE, int RELU>
__global__ __launch_bounds__(256) void mgemm(
    const ushort_t* __restrict__ A, const ushort_t* __restrict__ B,
    const void* __restrict__ biasA, const void* __restrict__ biasB,
    ushort_t* __restrict__ C, int K, int lda, int ldb, int ldc,
    long sA2, long sB2, long sC2, long boff, float alpha,
    const int* __restrict__ flagp)
{
    const int z = blockIdx.z;
    const long m0 = (long)blockIdx.y * 128;
    const long n0 = (long)blockIdx.x * 128;
    A += z * sA2;
    B += z * sB2;

    __shared__ __align__(16) ushort_t As[128 * 32];
    __shared__ __align__(16) ushort_t Bs[128 * 32];

    const int tid = threadIdx.x;
    const int wave = tid >> 6;
    const int lane = tid & 63;
    const int quad = lane >> 4;
    const int lrow = lane & 15;
    const int wm = (wave >> 1) * 64;
    const int wn = (wave & 1) * 64;

    float4v acc[4][4];
#pragma unroll
    for (int i = 0; i < 4; ++i)
#pragma unroll
        for (int j = 0; j < 4; ++j)
            acc[i][j] = (float4v){0.f, 0.f, 0.f, 0.f};

    for (int k0 = 0; k0 < K; k0 += 32) {
        __syncthreads();
#pragma unroll
        for (int p = 0; p < 2; ++p) {
            const int c = p * 256 + tid;
            const int row = c >> 2;
            const int kk = (c & 3) << 3;
            *reinterpret_cast<short8v*>(&As[c << 3]) =
                *reinterpret_cast<const short8v*>(&A[(m0 + row) * (long)lda + k0 + kk]);
            *reinterpret_cast<short8v*>(&Bs[c << 3]) =
                *reinterpret_cast<const short8v*>(&B[(n0 + row) * (long)ldb + k0 + kk]);
        }
        __syncthreads();

        short8v af[4], bfv[4];
#pragma unroll
        for (int i = 0; i < 4; ++i) {
            af[i]  = *reinterpret_cast<const short8v*>(&As[(wm + i * 16 + lrow) * 32 + quad * 8]);
            bfv[i] = *reinterpret_cast<const short8v*>(&Bs[(wn + i * 16 + lrow) * 32 + quad * 8]);
        }
#pragma unroll
        for (int mi = 0; mi < 4; ++mi)
#pragma unroll
            for (int ni = 0; ni < 4; ++ni)
                acc[mi][ni] = __builtin_amdgcn_mfma_f32_16x16x32_bf16(
                    af[mi], bfv[ni], acc[mi][ni], 0, 0, 0);
    }

    const int fbf = flagp ? *flagp : 0;
#pragma unroll
    for (int mi = 0; mi < 4; ++mi) {
#pragma unroll
        for (int ni = 0; ni < 4; ++ni) {
            const long col = n0 + wn + ni * 16 + lrow;
            const long row0 = m0 + wm + mi * 16 + quad * 4;
            float bv = 0.f;
            if (biasA) {
                const void* bp = biasA;
                long bn = col;
                if (biasB && col >= 1024) { bp = biasB; bn = col - 1024; }
                bv = fbf ? bf2f(((const ushort_t*)bp)[boff + bn])
                         : ((const float*)bp)[boff + bn];
            }
            if constexpr (CMODE == 1) {
#pragma unroll
                for (int r = 0; r < 4; ++r) {
                    float v = acc[mi][ni][r] * alpha + bv;
                    if (RELU) v = fmaxf(v, 0.f);
                    C[(long)z * sC2 + (row0 + r) * (long)ldc + col] = f2bf(v);
                }
            } else {
                ushort4 u;
                float v0 = acc[mi][ni][0] * alpha + bv;
                float v1 = acc[mi][ni][1] * alpha + bv;
                float v2 = acc[mi][ni][2] * alpha + bv;
                float v3 = acc[mi][ni][3] * alpha + bv;
                if (RELU) {
                    v0 = fmaxf(v0, 0.f); v1 = fmaxf(v1, 0.f);
                    v2 = fmaxf(v2, 0.f); v3 = fmaxf(v3, 0.f);
                }
                u.x = f2bf(v0); u.y = f2bf(v1); u.z = f2bf(v2); u.w = f2bf(v3);
                *reinterpret_cast<ushort4*>(&C[(long)z * sC2 + col * (long)ldc + row0]) = u;
            }
        }
    }
}

// ---------------------------------------------------------------------------
// Fused flash attention. Grid (16 q-tiles, 16 bh), 256 thr = 4 waves.
// Each block: Q-tile 64 rows of one (b,h); wave w owns Q-rows w*16..w*16+15
// (wave-private online-softmax state). K-tile = 32 keys staged to LDS;
// V staged from vT [bh][256 d][1024 t]. P routes C/D->A-layout through
// padded LDS (stride 40 ushorts; all pads break the mod-32-bank stride).
// In-place: attention out overwrites Q cols of qk (race-free: each block
// writes only its own rows x its own h-cols; K cols never written).
// scale = 1/sqrt(256) applied to S pre-softmax.
// ---------------------------------------------------------------------------
__global__ __launch_bounds__(256) void flash_attn(
    ushort_t* __restrict__ qk, const ushort_t* __restrict__ vT)
{
    const int qt = blockIdx.x;
    const int bh = blockIdx.y;
    const int b = bh >> 2, h = bh & 3;

    __shared__ __align__(16) ushort_t Ks[32 * 264];     // 16.9 KB
    __shared__ __align__(16) ushort_t Vs[256 * 40];     // 20.5 KB
    __shared__ __align__(16) ushort_t Ps[4][16 * 40];   //  5.1 KB

    const int tid = threadIdx.x;
    const int wave = tid >> 6;
    const int lane = tid & 63;
    const int quad = lane >> 4;
    const int lrow = lane & 15;

    const long qrow0 = (long)b * CT + qt * 64;
    const int qcol = h * 256;
    const int kcol = 1024 + h * 256;
    const long vbase = (long)bh * 256 * 1024;

    // Q A-fragments in registers: m = lrow (wave-row), k = kk*32 + quad*8 + j
    short8v qf[8];
#pragma unroll
    for (int kk = 0; kk < 8; ++kk)
        qf[kk] = *reinterpret_cast<const short8v*>(
            &qk[(qrow0 + wave * 16 + lrow) * 2048 + qcol + kk * 32 + quad * 8]);

    float m4[4], l4[4];
#pragma unroll
    for (int r = 0; r < 4; ++r) { m4[r] = -1e30f; l4[r] = 0.f; }
    float4v oacc[16];
#pragma unroll
    for (int i = 0; i < 16; ++i) oacc[i] = (float4v){0.f, 0.f, 0.f, 0.f};

    for (int t0 = 0; t0 < CT; t0 += 32) {
        __syncthreads();
        // stage K tile 32x256 and V tile 256x32 (1024 16B-chunks each)
#pragma unroll
        for (int p = 0; p < 4; ++p) {
            const int c = p * 256 + tid;
            {
                const int r = c >> 5, col = (c & 31) * 8;
                *reinterpret_cast<short8v*>(&Ks[r * 264 + col]) =
                    *reinterpret_cast<const short8v*>(
                        &qk[((long)b * CT + t0 + r) * 2048 + kcol + col]);
            }
            {
                const int r = c >> 2, col = (c & 3) * 8;
                *reinterpret_cast<short8v*>(&Vs[r * 40 + col]) =
                    *reinterpret_cast<const short8v*>(
                        &vT[vbase + (long)r * 1024 + t0 + col]);
            }
        }
        __syncthreads();

        // S strip: 16 q-rows x 32 keys, wave-private
        float4v sacc[2];
        sacc[0] = (float4v){0.f, 0.f, 0.f, 0.f};
        sacc[1] = (float4v){0.f, 0.f, 0.f, 0.f};
#pragma unroll
        for (int kk = 0; kk < 8; ++kk) {
#pragma unroll
            for (int ni = 0; ni < 2; ++ni) {
                short8v bk = *reinterpret_cast<const short8v*>(
                    &Ks[(ni * 16 + lrow) * 264 + kk * 32 + quad * 8]);
                sacc[ni] = __builtin_amdgcn_mfma_f32_16x16x32_bf16(
                    qf[kk], bk, sacc[ni], 0, 0, 0);
            }
        }
#pragma unroll
        for (int ni = 0; ni < 2; ++ni)
#pragma unroll
            for (int r = 0; r < 4; ++r)
                sacc[ni][r] *= 0.0625f;

        // online softmax: rows = quad*4+r; reduce across the 16 lrow lanes
        float alpha4[4];
#pragma unroll
        for (int r = 0; r < 4; ++r) {
            float mx = fmaxf(sacc[0][r], sacc[1][r]);
#pragma unroll
            for (int sh = 1; sh < 16; sh <<= 1)
                mx = fmaxf(mx, __shfl_xor(mx, sh));
            const float mnew = fmaxf(m4[r], mx);
            alpha4[r] = __expf(m4[r] - mnew);
            m4[r] = mnew;
        }
#pragma unroll
        for (int ni = 0; ni < 2; ++ni)
#pragma unroll
            for (int r = 0; r < 4; ++r) {
                const float pv = __expf(sacc[ni][r] - m4[r]);
                sacc[ni][r] = pv;
                Ps[wave][(quad * 4 + r) * 40 + ni * 16 + lrow] = f2bf(pv);
            }
#pragma unroll
        for (int r = 0; r < 4; ++r) {
            float s = sacc[0][r] + sacc[1][r];
#pragma unroll
            for (int sh = 1; sh < 16; sh <<= 1)
                s += __shfl_xor(s, sh);
            l4[r] = l4[r] * alpha4[r] + s;
        }
#pragma unroll
        for (int ni = 0; ni < 16; ++ni)
#pragma unroll
            for (int r = 0; r < 4; ++r)
                oacc[ni][r] *= alpha4[r];

        // O += P(16x32) @ V(32x256): A = Ps[m=lrow][k=quad*8+j], B = Vs[d][t]
        {
            short8v ap = *reinterpret_cast<const short8v*>(
                &Ps[wave][lrow * 40 + quad * 8]);
#pragma unroll
            for (int ni = 0; ni < 16; ++ni) {
                short8v bv = *reinterpret_cast<const short8v*>(
                    &Vs[(ni * 16 + lrow) * 40 + quad * 8]);
                oacc[ni] = __builtin_amdgcn_mfma_f32_16x16x32_bf16(
                    ap, bv, oacc[ni], 0, 0, 0);
            }
        }
    }

    // epilogue: O /= l; write into qk Q-cols (own rows x own h-cols only)
#pragma unroll
    for (int ni = 0; ni < 16; ++ni) {
#pragma unroll
        for (int r = 0; r < 4; ++r) {
            const float v = oacc[ni][r] / l4[r];
            qk[(qrow0 + wave * 16 + quad * 4 + r) * 2048 + qcol + ni * 16 + lrow]
                = f2bf(v);
        }
    }
}

// ---------------------------------------------------------------------------
// Residual + LayerNorm, bf16 stream, fp32 stats.
// ---------------------------------------------------------------------------
__global__ __launch_bounds__(256) void ln_bf(
    const ushort_t* __restrict__ o, const ushort_t* __restrict__ res,
    const void* __restrict__ sc, const void* __restrict__ bi,
    ushort_t* __restrict__ out, long loff, const int* __restrict__ flagp)
{
    const int fbf = *flagp;
    const long row = (long)blockIdx.x * CD;
    const int t = threadIdx.x;
    const float x = bf2f(o[row + t]) + bf2f(res[row + t]);

    __shared__ float r1[256];
    __shared__ float r2[256];
    r1[t] = x;
    r2[t] = x * x;
    __syncthreads();
    for (int s = 128; s > 0; s >>= 1) {
        if (t < s) { r1[t] += r1[t + s]; r2[t] += r2[t + s]; }
        __syncthreads();
    }
    const float mean = r1[0] * (1.0f / CD);
    const float var = r2[0] * (1.0f / CD) - mean * mean;
    const float rstd = rsqrtf(var + 1e-5f);
    const float s_v = fbf ? bf2f(((const ushort_t*)sc)[loff + t]) : ((const float*)sc)[loff + t];
    const float b_v = fbf ? bf2f(((const ushort_t*)bi)[loff + t]) : ((const float*)bi)[loff + t];
    out[row + t] = f2bf((x - mean) * rstd * s_v + b_v);
}

__global__ __launch_bounds__(256) void in_convert(
    const void* __restrict__ in, ushort_t* __restrict__ x,
    const int* __restrict__ flagp)
{
    const int fbf = *flagp;
    const long i = ((long)blockIdx.x * 256 + threadIdx.x) << 2;
    if (fbf) {
        *reinterpret_cast<ushort4*>(x + i) =
            *reinterpret_cast<const ushort4*>((const ushort_t*)in + i);
    } else {
        float4 f = *reinterpret_cast<const float4*>((const float*)in + i);
        ushort4 u;
        u.x = f2bf(f.x); u.y = f2bf(f.y); u.z = f2bf(f.z); u.w = f2bf(f.w);
        *reinterpret_cast<ushort4*>(x + i) = u;
    }
}

__global__ __launch_bounds__(256) void out_write(
    const ushort_t* __restrict__ x, void* __restrict__ out,
    const int* __restrict__ flagp)
{
    const int fbf = *flagp;
    const long i = ((long)blockIdx.x * 256 + threadIdx.x) << 2;
    ushort4 u = *reinterpret_cast<const ushort4*>(x + i);
    if (fbf) {
        *reinterpret_cast<ushort4*>((ushort_t*)out + i) = u;
    } else {
        float4 f = make_float4(bf2f(u.x), bf2f(u.y), bf2f(u.z), bf2f(u.w));
        *reinterpret_cast<float4*>((float*)out + i) = f;
    }
}

// ---------------------------------------------------------------------------
// Orchestration. ws layout 34.3 MB (S eliminated by flash attention).
// ---------------------------------------------------------------------------
extern "C" void kernel_launch(void* const* d_in, const int* in_sizes, int n_in,
                              void* d_out, int out_size, void* d_ws, size_t ws_size,
                              hipStream_t stream)
{
    const void* queries = d_in[0];
    const void* Wq = d_in[1];  const void* bq = d_in[2];
    const void* Wk = d_in[3];  const void* bk = d_in[4];
    const void* Wv = d_in[5];  const void* bv = d_in[6];
    const void* Wo = d_in[7];  const void* bo = d_in[8];
    const void* ln1s = d_in[9];  const void* ln1b = d_in[10];
    const void* W1 = d_in[11]; const void* b1 = d_in[12];
    const void* W2 = d_in[13]; const void* b2 = d_in[14];
    const void* ln2s = d_in[15]; const void* ln2b = d_in[16];

    char* p = (char*)d_ws;
    int* flagp = (int*)p;            p += 256;
    ushort_t* wqkT = (ushort_t*)p;   p += (long)CL * 2048 * 256 * 2;   // 2 MB
    ushort_t* wvT  = (ushort_t*)p;   p += (long)CL * 1024 * 256 * 2;   // 1 MB
    ushort_t* woT  = (ushort_t*)p;   p += (long)CL * 256 * 1024 * 2;   // 1 MB
    ushort_t* w1T  = (ushort_t*)p;   p += (long)CL * 1024 * 256 * 2;   // 1 MB
    ushort_t* w2T  = (ushort_t*)p;   p += (long)CL * 256 * 1024 * 2;   // 1 MB
    ushort_t* xa   = (ushort_t*)p;   p += (long)NROW * CD * 2;         // 2 MB
    ushort_t* xb   = (ushort_t*)p;   p += (long)NROW * CD * 2;         // 2 MB
    ushort_t* qk   = (ushort_t*)p;   p += (long)NROW * 2048 * 2;       // 16 MB
    ushort_t* vT   = (ushort_t*)p;   p += (long)CB * CH * 256 * 1024 * 2; // 8 MB
    ushort_t* h    = vT;  // MLP hidden reuses vT (dead after attention)

    detect_kernel<<<1, 256, 0, stream>>>((const ushort_t*)Wq, 2048, flagp);

    tconv_kernel<<<dim3(32, 8, CL), 256, 0, stream>>>(
        Wq, wqkT, 256, 1024, 256 * 1024, 2048 * 256, flagp);
    tconv_kernel<<<dim3(32, 8, CL), 256, 0, stream>>>(
        Wk, wqkT + 1024 * 256, 256, 1024, 256 * 1024, 2048 * 256, flagp);
    tconv_kernel<<<dim3(32, 8, CL), 256, 0, stream>>>(
        Wv, wvT, 256, 1024, 256 * 1024, 1024 * 256, flagp);
    tconv_kernel<<<dim3(8, 32, CL), 256, 0, stream>>>(
        Wo, woT, 1024, 256, 1024 * 256, 256 * 1024, flagp);
    tconv_kernel<<<dim3(32, 8, CL), 256, 0, stream>>>(
        W1, w1T, 256, 1024, 256 * 1024, 1024 * 256, flagp);
    tconv_kernel<<<dim3(8, 32, CL), 256, 0, stream>>>(
        W2, w2T, 1024, 256, 1024 * 256, 256 * 1024, flagp);

    in_convert<<<(NROW * CD) / 1024, 256, 0, stream>>>(queries, xa, flagp);

    for (int l = 0; l < CL; ++l) {
        // 1) Q|K projection: xa [4096,256] @ wqkT[l]^T -> qk [4096,2048]
        mgemm<1, 0><<<dim3(16, 32, 1), 256, 0, stream>>>(
            xa, wqkT + (long)l * 2048 * 256, bq, bk, qk,
            256, 256, 256, 2048, 0, 0, 0, (long)l * 1024, 1.0f, flagp);
        // 2) V projection, transposed write -> vT[b][h][d][t]
        mgemm<2, 0><<<dim3(8, 8, CB), 256, 0, stream>>>(
            xa, wvT + (long)l * 1024 * 256, bv, nullptr, vT,
            256, 256, 256, 1024, (long)CT * 256, 0, (long)CT * CT,
            (long)l * 1024, 1.0f, flagp);

        // 3) fused attention (in-place: out overwrites Q cols of qk)
        flash_attn<<<dim3(16, 16, 1), 256, 0, stream>>>(qk, vT);

        // 4) O projection: ao (qk cols 0..1023) @ woT[l]^T + bo -> xb
        mgemm<1, 0><<<dim3(2, 32, 1), 256, 0, stream>>>(
            qk, woT + (long)l * 256 * 1024, bo, nullptr, xb,
            1024, 2048, 1024, 256, 0, 0, 0, (long)l * 256, 1.0f, flagp);
        // 5) xa = LN(xb + xa)
        ln_bf<<<NROW, 256, 0, stream>>>(xb, xa, ln1s, ln1b, xa,
                                        (long)l * 256, flagp);
        // 6) h = relu(xa @ w1T[l]^T + b1)
        mgemm<1, 1><<<dim3(8, 32, 1), 256, 0, stream>>>(
            xa, w1T + (long)l * 1024 * 256, b1, nullptr, h,
            256, 256, 256, 1024, 0, 0, 0, (long)l * 1024, 1.0f, flagp);
        // 7) m = h @ w2T[l]^T + b2 -> xb
        mgemm<1, 0><<<dim3(2, 32, 1), 256, 0, stream>>>(
            h, w2T + (long)l * 256 * 1024, b2, nullptr, xb,
            1024, 1024, 1024, 256, 0, 0, 0, (long)l * 256, 1.0f, flagp);
        // 8) xa = LN(xb + xa)
        ln_bf<<<NROW, 256, 0, stream>>>(xb, xa, ln2s, ln2b, xa,
                                        (long)l * 256, flagp);
    }

    out_write<<<(NROW * CD) / 1024, 256, 0, stream>>>(xa, d_out, flagp);
}

// Round 6
// 375.571 us; speedup vs baseline: 3.8352x; 1.2582x over previous
//
#include <hip/hip_runtime.h>
#include <hip/hip_bf16.h>

#define CL 2
#define CB 4
#define CT 1024
#define CD 256
#define CH 4
#define CM 1024
#define CHD (CH * CD)      // 1024
#define NROW (CB * CT)     // 4096

typedef unsigned short ushort_t;
typedef __attribute__((ext_vector_type(8))) short short8v;   // 8 bf16 (4 VGPR)
typedef __attribute__((ext_vector_type(4))) float float4v;   // MFMA C/D frag

__device__ __forceinline__ float bf2f(unsigned short u) {
    return __uint_as_float(((unsigned int)u) << 16);
}
__device__ __forceinline__ unsigned short f2bf(float f) {
    unsigned int x = __float_as_uint(f);
    return (unsigned short)((x + 0x7fffu + ((x >> 16) & 1u)) >> 16);
}

// ---------------------------------------------------------------------------
// Input-dtype detection (2048 elems; fp32-underlying -> ~430 anomalies, bf16 0)
// ---------------------------------------------------------------------------
__global__ __launch_bounds__(256) void detect_kernel(
    const ushort_t* __restrict__ w, int n, int* __restrict__ flag)
{
    __shared__ int red[256];
    int c = 0;
    for (int i = threadIdx.x; i < n; i += 256) {
        float v = bf2f(w[i]);
        if (!(fabsf(v) <= 1e6f)) c++;
    }
    red[threadIdx.x] = c;
    __syncthreads();
    for (int s = 128; s > 0; s >>= 1) {
        if (threadIdx.x < s) red[threadIdx.x] += red[threadIdx.x + s];
        __syncthreads();
    }
    if (threadIdx.x == 0) flag[0] = (red[0] < 8) ? 1 : 0;
}

// ---------------------------------------------------------------------------
// Weight transpose+convert: in [Z][R][C] (+ioff elems, dtype per flag) ->
// out bf16 [Z][C][R].
// ---------------------------------------------------------------------------
__global__ __launch_bounds__(256) void tconv_kernel(
    const void* __restrict__ in, ushort_t* __restrict__ out,
    int R, int C, long inzs, long outzs, long ioff,
    const int* __restrict__ flagp)
{
    const int fbf = *flagp;
    __shared__ float tile[32][33];
    const long zi = ioff + (long)blockIdx.z * inzs;
    const long zo = (long)blockIdx.z * outzs;
    const int r0 = blockIdx.y * 32;
    const int c0 = blockIdx.x * 32;
    const int tx = threadIdx.x & 31;
    const int ty = threadIdx.x >> 5;
#pragma unroll
    for (int i = 0; i < 32; i += 8) {
        const long idx = zi + (long)(r0 + ty + i) * C + c0 + tx;
        tile[ty + i][tx] = fbf ? bf2f(((const ushort_t*)in)[idx])
                               : ((const float*)in)[idx];
    }
    __syncthreads();
#pragma unroll
    for (int i = 0; i < 32; i += 8)
        out[zo + (long)(c0 + ty + i) * R + r0 + tx] = f2bf(tile[tx][ty + i]);
}

// ---------------------------------------------------------------------------
// MFMA GEMM 128x128 (verified r4/r5): C[z] = relu?(alpha * A[z]B[z]^T + bias)
// A bf16 [MxK](lda); B bf16 [NxK](ldb); CMODE 1 row-major, 2 transposed write.
// ---------------------------------------------------------------------------
template <int CMODE, int RELU>
__global__ __launch_bounds__(256) void mgemm(
    const ushort_t* __restrict__ A, const ushort_t* __restrict__ B,
    const void* __restrict__ biasA, const void* __restrict__ biasB,
    ushort_t* __restrict__ C, int K, int lda, int ldb, int ldc,
    long sA2, long sB2, long sC2, long boff, float alpha,
    const int* __restrict__ flagp)
{
    const int z = blockIdx.z;
    const long m0 = (long)blockIdx.y * 128;
    const long n0 = (long)blockIdx.x * 128;
    A += z * sA2;
    B += z * sB2;

    __shared__ __align__(16) ushort_t As[128 * 32];
    __shared__ __align__(16) ushort_t Bs[128 * 32];

    const int tid = threadIdx.x;
    const int wave = tid >> 6;
    const int lane = tid & 63;
    const int quad = lane >> 4;
    const int lrow = lane & 15;
    const int wm = (wave >> 1) * 64;
    const int wn = (wave & 1) * 64;

    float4v acc[4][4];
#pragma unroll
    for (int i = 0; i < 4; ++i)
#pragma unroll
        for (int j = 0; j < 4; ++j)
            acc[i][j] = (float4v){0.f, 0.f, 0.f, 0.f};

    for (int k0 = 0; k0 < K; k0 += 32) {
        __syncthreads();
#pragma unroll
        for (int p = 0; p < 2; ++p) {
            const int c = p * 256 + tid;
            const int row = c >> 2;
            const int kk = (c & 3) << 3;
            *reinterpret_cast<short8v*>(&As[c << 3]) =
                *reinterpret_cast<const short8v*>(&A[(m0 + row) * (long)lda + k0 + kk]);
            *reinterpret_cast<short8v*>(&Bs[c << 3]) =
                *reinterpret_cast<const short8v*>(&B[(n0 + row) * (long)ldb + k0 + kk]);
        }
        __syncthreads();

        short8v af[4], bfv[4];
#pragma unroll
        for (int i = 0; i < 4; ++i) {
            af[i]  = *reinterpret_cast<const short8v*>(&As[(wm + i * 16 + lrow) * 32 + quad * 8]);
            bfv[i] = *reinterpret_cast<const short8v*>(&Bs[(wn + i * 16 + lrow) * 32 + quad * 8]);
        }
#pragma unroll
        for (int mi = 0; mi < 4; ++mi)
#pragma unroll
            for (int ni = 0; ni < 4; ++ni)
                acc[mi][ni] = __builtin_amdgcn_mfma_f32_16x16x32_bf16(
                    af[mi], bfv[ni], acc[mi][ni], 0, 0, 0);
    }

    const int fbf = flagp ? *flagp : 0;
#pragma unroll
    for (int mi = 0; mi < 4; ++mi) {
#pragma unroll
        for (int ni = 0; ni < 4; ++ni) {
            const long col = n0 + wn + ni * 16 + lrow;
            const long row0 = m0 + wm + mi * 16 + quad * 4;
            float bv = 0.f;
            if (biasA) {
                const void* bp = biasA;
                long bn = col;
                if (biasB && col >= 1024) { bp = biasB; bn = col - 1024; }
                bv = fbf ? bf2f(((const ushort_t*)bp)[boff + bn])
                         : ((const float*)bp)[boff + bn];
            }
            if constexpr (CMODE == 1) {
#pragma unroll
                for (int r = 0; r < 4; ++r) {
                    float v = acc[mi][ni][r] * alpha + bv;
                    if (RELU) v = fmaxf(v, 0.f);
                    C[(long)z * sC2 + (row0 + r) * (long)ldc + col] = f2bf(v);
                }
            } else {
                ushort4 u;
                u.x = f2bf(acc[mi][ni][0] * alpha + bv);
                u.y = f2bf(acc[mi][ni][1] * alpha + bv);
                u.z = f2bf(acc[mi][ni][2] * alpha + bv);
                u.w = f2bf(acc[mi][ni][3] * alpha + bv);
                *reinterpret_cast<ushort4*>(&C[(long)z * sC2 + col * (long)ldc + row0]) = u;
            }
        }
    }
}

// ---------------------------------------------------------------------------
// mgemm64s: 64x64-tile split-K GEMM -> fp32 partials. Grid (N/64, M/64, 2).
// A: AMODE 0 plain bf16 [M][lda]; AMODE 1 = combined attention partials:
//    A=op0, Ap1=op1 (both [4096][1024] bf16 unnormalized), ml [2][16][1024]
//    (m,l per chunk/bh/row) -> combine on the fly during staging.
// B: bf16 [N=256 rows][ldb] (pre-transposed weight).
// P: fp32 [2][4096][256]; chunk z covers K [z*K2, z*K2+K2).
// 4 waves, each 32x32 (2x2 mfma tiles).
// ---------------------------------------------------------------------------
template <int AMODE>
__global__ __launch_bounds__(256) void mgemm64s(
    const ushort_t* __restrict__ A, const ushort_t* __restrict__ Ap1,
    const float2* __restrict__ ml, const ushort_t* __restrict__ B,
    float* __restrict__ P, int K2, int lda, int ldb)
{
    const int z = blockIdx.z;
    const long m0 = (long)blockIdx.y * 64;
    const long n0 = (long)blockIdx.x * 64;
    const int k_beg = z * K2;

    __shared__ __align__(16) ushort_t As[64 * 32];
    __shared__ __align__(16) ushort_t Bs[64 * 32];

    const int tid = threadIdx.x;
    const int wave = tid >> 6;
    const int lane = tid & 63;
    const int quad = lane >> 4;
    const int lrow = lane & 15;
    const int wm = (wave >> 1) * 32;
    const int wn = (wave & 1) * 32;

    const int ar = tid >> 2;              // 0..63
    const int ak = (tid & 3) << 3;        // 0,8,16,24

    float4v acc[2][2];
#pragma unroll
    for (int i = 0; i < 2; ++i)
#pragma unroll
        for (int j = 0; j < 2; ++j)
            acc[i][j] = (float4v){0.f, 0.f, 0.f, 0.f};

    for (int k0 = k_beg; k0 < k_beg + K2; k0 += 32) {
        __syncthreads();
        if constexpr (AMODE == 0) {
            *reinterpret_cast<short8v*>(&As[tid << 3]) =
                *reinterpret_cast<const short8v*>(&A[(m0 + ar) * (long)lda + k0 + ak]);
        } else {
            const long m = m0 + ar;
            const int hh = (k0 + ak) >> 8;
            const int bh = ((int)(m >> 10) << 2) + hh;
            const int trow = (int)(m & 1023);
            const float2 v0 = ml[bh * 1024 + trow];
            const float2 v1 = ml[(16 + bh) * 1024 + trow];
            const float mm = fmaxf(v0.x, v1.x);
            const float a0 = __expf(v0.x - mm);
            const float a1 = __expf(v1.x - mm);
            const float inv = 1.0f / (v0.y * a0 + v1.y * a1);
            const ushort4 u0a = *reinterpret_cast<const ushort4*>(&A[m * 1024 + k0 + ak]);
            const ushort4 u0b = *reinterpret_cast<const ushort4*>(&A[m * 1024 + k0 + ak + 4]);
            const ushort4 u1a = *reinterpret_cast<const ushort4*>(&Ap1[m * 1024 + k0 + ak]);
            const ushort4 u1b = *reinterpret_cast<const ushort4*>(&Ap1[m * 1024 + k0 + ak + 4]);
            short8v t8;
            t8[0] = (short)f2bf((bf2f(u0a.x) * a0 + bf2f(u1a.x) * a1) * inv);
            t8[1] = (short)f2bf((bf2f(u0a.y) * a0 + bf2f(u1a.y) * a1) * inv);
            t8[2] = (short)f2bf((bf2f(u0a.z) * a0 + bf2f(u1a.z) * a1) * inv);
            t8[3] = (short)f2bf((bf2f(u0a.w) * a0 + bf2f(u1a.w) * a1) * inv);
            t8[4] = (short)f2bf((bf2f(u0b.x) * a0 + bf2f(u1b.x) * a1) * inv);
            t8[5] = (short)f2bf((bf2f(u0b.y) * a0 + bf2f(u1b.y) * a1) * inv);
            t8[6] = (short)f2bf((bf2f(u0b.z) * a0 + bf2f(u1b.z) * a1) * inv);
            t8[7] = (short)f2bf((bf2f(u0b.w) * a0 + bf2f(u1b.w) * a1) * inv);
            *reinterpret_cast<short8v*>(&As[tid << 3]) = t8;
        }
        *reinterpret_cast<short8v*>(&Bs[tid << 3]) =
            *reinterpret_cast<const short8v*>(&B[(n0 + ar) * (long)ldb + k0 + ak]);
        __syncthreads();

        short8v af[2], bfv[2];
#pragma unroll
        for (int i = 0; i < 2; ++i) {
            af[i]  = *reinterpret_cast<const short8v*>(&As[(wm + i * 16 + lrow) * 32 + quad * 8]);
            bfv[i] = *reinterpret_cast<const short8v*>(&Bs[(wn + i * 16 + lrow) * 32 + quad * 8]);
        }
#pragma unroll
        for (int mi = 0; mi < 2; ++mi)
#pragma unroll
            for (int ni = 0; ni < 2; ++ni)
                acc[mi][ni] = __builtin_amdgcn_mfma_f32_16x16x32_bf16(
                    af[mi], bfv[ni], acc[mi][ni], 0, 0, 0);
    }

    float* Pz = P + (long)z * NROW * CD;
#pragma unroll
    for (int mi = 0; mi < 2; ++mi)
#pragma unroll
        for (int ni = 0; ni < 2; ++ni) {
            const long col = n0 + wn + ni * 16 + lrow;
            const long row0 = m0 + wm + mi * 16 + quad * 4;
#pragma unroll
            for (int r = 0; r < 4; ++r)
                Pz[(row0 + r) * CD + col] = acc[mi][ni][r];
        }
}

// ---------------------------------------------------------------------------
// Flash attention, KV-split x2. Grid 512 linear: bh = x&15 (same-bh blocks
// land on one XCD for K/V L2 residency), qt = (x>>4)&15, ck = x>>8.
// qk is CONST (Q cols 0..1023, K cols 1024..2047). Each chunk writes
// UNNORMALIZED partial O (bf16) to op0/op1 [4096][1024] and (m,l) to ml.
// 2 blocks/CU -> latency overlap (round-5: 1/CU, 67% stall).
// ---------------------------------------------------------------------------
__global__ __launch_bounds__(256) void flash_attn(
    const ushort_t* __restrict__ qk, const ushort_t* __restrict__ vT,
    ushort_t* __restrict__ op0, ushort_t* __restrict__ op1,
    float2* __restrict__ ml)
{
    const int bx = blockIdx.x;
    const int bh = bx & 15;
    const int qt = (bx >> 4) & 15;
    const int ck = bx >> 8;
    const int b = bh >> 2, h = bh & 3;

    __shared__ __align__(16) ushort_t Ks[32 * 264];
    __shared__ __align__(16) ushort_t Vs[256 * 40];
    __shared__ __align__(16) ushort_t Ps[4][16 * 40];

    const int tid = threadIdx.x;
    const int wave = tid >> 6;
    const int lane = tid & 63;
    const int quad = lane >> 4;
    const int lrow = lane & 15;

    const long qrow0 = (long)b * CT + qt * 64;
    const int qcol = h * 256;
    const int kcol = 1024 + h * 256;
    const long vbase = (long)bh * 256 * 1024;

    short8v qf[8];
#pragma unroll
    for (int kk = 0; kk < 8; ++kk)
        qf[kk] = *reinterpret_cast<const short8v*>(
            &qk[(qrow0 + wave * 16 + lrow) * 2048 + qcol + kk * 32 + quad * 8]);

    float m4[4], l4[4];
#pragma unroll
    for (int r = 0; r < 4; ++r) { m4[r] = -1e30f; l4[r] = 0.f; }
    float4v oacc[16];
#pragma unroll
    for (int i = 0; i < 16; ++i) oacc[i] = (float4v){0.f, 0.f, 0.f, 0.f};

    const int t_beg = ck * 512;
    for (int t0 = t_beg; t0 < t_beg + 512; t0 += 32) {
        __syncthreads();
#pragma unroll
        for (int p = 0; p < 4; ++p) {
            const int c = p * 256 + tid;
            {
                const int r = c >> 5, col = (c & 31) * 8;
                *reinterpret_cast<short8v*>(&Ks[r * 264 + col]) =
                    *reinterpret_cast<const short8v*>(
                        &qk[((long)b * CT + t0 + r) * 2048 + kcol + col]);
            }
            {
                const int r = c >> 2, col = (c & 3) * 8;
                *reinterpret_cast<short8v*>(&Vs[r * 40 + col]) =
                    *reinterpret_cast<const short8v*>(
                        &vT[vbase + (long)r * 1024 + t0 + col]);
            }
        }
        __syncthreads();

        float4v sacc[2];
        sacc[0] = (float4v){0.f, 0.f, 0.f, 0.f};
        sacc[1] = (float4v){0.f, 0.f, 0.f, 0.f};
#pragma unroll
        for (int kk = 0; kk < 8; ++kk) {
#pragma unroll
            for (int ni = 0; ni < 2; ++ni) {
                short8v bk = *reinterpret_cast<const short8v*>(
                    &Ks[(ni * 16 + lrow) * 264 + kk * 32 + quad * 8]);
                sacc[ni] = __builtin_amdgcn_mfma_f32_16x16x32_bf16(
                    qf[kk], bk, sacc[ni], 0, 0, 0);
            }
        }
#pragma unroll
        for (int ni = 0; ni < 2; ++ni)
#pragma unroll
            for (int r = 0; r < 4; ++r)
                sacc[ni][r] *= 0.0625f;

        float alpha4[4];
#pragma unroll
        for (int r = 0; r < 4; ++r) {
            float mx = fmaxf(sacc[0][r], sacc[1][r]);
#pragma unroll
            for (int sh = 1; sh < 16; sh <<= 1)
                mx = fmaxf(mx, __shfl_xor(mx, sh));
            const float mnew = fmaxf(m4[r], mx);
            alpha4[r] = __expf(m4[r] - mnew);
            m4[r] = mnew;
        }
#pragma unroll
        for (int ni = 0; ni < 2; ++ni)
#pragma unroll
            for (int r = 0; r < 4; ++r) {
                const float pv = __expf(sacc[ni][r] - m4[r]);
                sacc[ni][r] = pv;
                Ps[wave][(quad * 4 + r) * 40 + ni * 16 + lrow] = f2bf(pv);
            }
#pragma unroll
        for (int r = 0; r < 4; ++r) {
            float s = sacc[0][r] + sacc[1][r];
#pragma unroll
            for (int sh = 1; sh < 16; sh <<= 1)
                s += __shfl_xor(s, sh);
            l4[r] = l4[r] * alpha4[r] + s;
        }
#pragma unroll
        for (int ni = 0; ni < 16; ++ni)
#pragma unroll
            for (int r = 0; r < 4; ++r)
                oacc[ni][r] *= alpha4[r];

        {
            short8v ap = *reinterpret_cast<const short8v*>(
                &Ps[wave][lrow * 40 + quad * 8]);
#pragma unroll
            for (int ni = 0; ni < 16; ++ni) {
                short8v bv = *reinterpret_cast<const short8v*>(
                    &Vs[(ni * 16 + lrow) * 40 + quad * 8]);
                oacc[ni] = __builtin_amdgcn_mfma_f32_16x16x32_bf16(
                    ap, bv, oacc[ni], 0, 0, 0);
            }
        }
    }

    // epilogue: unnormalized partial O + (m,l)
#pragma unroll
    for (int r = 0; r < 4; ++r)
        if (lrow == 0)
            ml[((ck << 4) + bh) * 1024 + qt * 64 + wave * 16 + quad * 4 + r] =
                make_float2(m4[r], l4[r]);

    ushort_t* op = ck ? op1 : op0;
#pragma unroll
    for (int ni = 0; ni < 16; ++ni)
#pragma unroll
        for (int r = 0; r < 4; ++r)
            op[(qrow0 + wave * 16 + quad * 4 + r) * 1024 + (h << 8) + ni * 16 + lrow]
                = f2bf(oacc[ni][r]);
}

// ---------------------------------------------------------------------------
// ln_p: x = P0[row]+P1[row] + gbias + res; out = LN(x)*s + b (bf16).
// P: fp32 [2][4096][256]; gb from d_in (+gboff, dtype per flag).
// ---------------------------------------------------------------------------
__global__ __launch_bounds__(256) void ln_p(
    const float* __restrict__ p, const void* __restrict__ gb, long gboff,
    const ushort_t* __restrict__ res, const void* __restrict__ sc,
    const void* __restrict__ bi, ushort_t* __restrict__ out, long loff,
    const int* __restrict__ flagp)
{
    const int fbf = *flagp;
    const long row = (long)blockIdx.x * CD;
    const int t = threadIdx.x;
    const float gbv = fbf ? bf2f(((const ushort_t*)gb)[gboff + t])
                          : ((const float*)gb)[gboff + t];
    const float x = p[row + t] + p[(long)NROW * CD + row + t] + gbv + bf2f(res[row + t]);

    __shared__ float r1[256];
    __shared__ float r2[256];
    r1[t] = x;
    r2[t] = x * x;
    __syncthreads();
    for (int s = 128; s > 0; s >>= 1) {
        if (t < s) { r1[t] += r1[t + s]; r2[t] += r2[t + s]; }
        __syncthreads();
    }
    const float mean = r1[0] * (1.0f / CD);
    const float var = r2[0] * (1.0f / CD) - mean * mean;
    const float rstd = rsqrtf(var + 1e-5f);
    const float s_v = fbf ? bf2f(((const ushort_t*)sc)[loff + t]) : ((const float*)sc)[loff + t];
    const float b_v = fbf ? bf2f(((const ushort_t*)bi)[loff + t]) : ((const float*)bi)[loff + t];
    out[row + t] = f2bf((x - mean) * rstd * s_v + b_v);
}

__global__ __launch_bounds__(256) void in_convert(
    const void* __restrict__ in, ushort_t* __restrict__ x,
    const int* __restrict__ flagp)
{
    const int fbf = *flagp;
    const long i = ((long)blockIdx.x * 256 + threadIdx.x) << 2;
    if (fbf) {
        *reinterpret_cast<ushort4*>(x + i) =
            *reinterpret_cast<const ushort4*>((const ushort_t*)in + i);
    } else {
        float4 f = *reinterpret_cast<const float4*>((const float*)in + i);
        ushort4 u;
        u.x = f2bf(f.x); u.y = f2bf(f.y); u.z = f2bf(f.z); u.w = f2bf(f.w);
        *reinterpret_cast<ushort4*>(x + i) = u;
    }
}

__global__ __launch_bounds__(256) void out_write(
    const ushort_t* __restrict__ x, void* __restrict__ out,
    const int* __restrict__ flagp)
{
    const int fbf = *flagp;
    const long i = ((long)blockIdx.x * 256 + threadIdx.x) << 2;
    ushort4 u = *reinterpret_cast<const ushort4*>(x + i);
    if (fbf) {
        *reinterpret_cast<ushort4*>((ushort_t*)out + i) = u;
    } else {
        float4 f = make_float4(bf2f(u.x), bf2f(u.y), bf2f(u.z), bf2f(u.w));
        *reinterpret_cast<float4*>((float*)out + i) = f;
    }
}

// ---------------------------------------------------------------------------
// Orchestration. ws = 47.0 MB (< 48 known-safe).
// ---------------------------------------------------------------------------
extern "C" void kernel_launch(void* const* d_in, const int* in_sizes, int n_in,
                              void* d_out, int out_size, void* d_ws, size_t ws_size,
                              hipStream_t stream)
{
    const void* queries = d_in[0];
    const void* Wq = d_in[1];  const void* bq = d_in[2];
    const void* Wk = d_in[3];  const void* bk = d_in[4];
    const void* Wv = d_in[5];  const void* bv = d_in[6];
    const void* Wo = d_in[7];  const void* bo = d_in[8];
    const void* ln1s = d_in[9];  const void* ln1b = d_in[10];
    const void* W1 = d_in[11]; const void* b1 = d_in[12];
    const void* W2 = d_in[13]; const void* b2 = d_in[14];
    const void* ln2s = d_in[15]; const void* ln2b = d_in[16];

    char* p = (char*)d_ws;
    int* flagp = (int*)p;            p += 256;
    ushort_t* wqkT = (ushort_t*)p;   p += (long)CL * 2048 * 256 * 2;   // 2 MB
    ushort_t* wvT  = (ushort_t*)p;   p += (long)CL * 1024 * 256 * 2;   // 1 MB
    ushort_t* w1T  = (ushort_t*)p;   p += (long)CL * 1024 * 256 * 2;   // 1 MB
    ushort_t* wscr = (ushort_t*)p;   p += (long)256 * 1024 * 2;        // 0.5 MB
    ushort_t* xa   = (ushort_t*)p;   p += (long)NROW * CD * 2;         // 2 MB
    ushort_t* qk   = (ushort_t*)p;   p += (long)NROW * 2048 * 2;       // 16 MB
    ushort_t* vT   = (ushort_t*)p;   p += (long)16 * 256 * 1024 * 2;   // 8 MB
    ushort_t* op0  = (ushort_t*)p;   p += (long)NROW * 1024 * 2;       // 8 MB
    ushort_t* op1  = (ushort_t*)p;   p += (long)NROW * 1024 * 2;       // 8 MB
    float2*   ml   = (float2*)p;     p += (long)2 * 16 * 1024 * 8;     // 0.25 MB
    ushort_t* h    = vT;             // MLP hidden reuses vT
    float*    pgem = (float*)qk;     // fp32 GEMM partials reuse qk (dead post-flash)

    detect_kernel<<<1, 256, 0, stream>>>((const ushort_t*)Wq, 2048, flagp);

    tconv_kernel<<<dim3(32, 8, CL), 256, 0, stream>>>(
        Wq, wqkT, 256, 1024, 256 * 1024, 2048 * 256, 0, flagp);
    tconv_kernel<<<dim3(32, 8, CL), 256, 0, stream>>>(
        Wk, wqkT + 1024 * 256, 256, 1024, 256 * 1024, 2048 * 256, 0, flagp);
    tconv_kernel<<<dim3(32, 8, CL), 256, 0, stream>>>(
        Wv, wvT, 256, 1024, 256 * 1024, 1024 * 256, 0, flagp);
    tconv_kernel<<<dim3(32, 8, CL), 256, 0, stream>>>(
        W1, w1T, 256, 1024, 256 * 1024, 1024 * 256, 0, flagp);

    in_convert<<<(NROW * CD) / 1024, 256, 0, stream>>>(queries, xa, flagp);

    for (int l = 0; l < CL; ++l) {
        // 1) Q|K projection -> qk [4096,2048]
        mgemm<1, 0><<<dim3(16, 32, 1), 256, 0, stream>>>(
            xa, wqkT + (long)l * 2048 * 256, bq, bk, qk,
            256, 256, 256, 2048, 0, 0, 0, (long)l * 1024, 1.0f, flagp);
        // 2) V projection, transposed write -> vT[bh][d][t]
        mgemm<2, 0><<<dim3(8, 8, CB), 256, 0, stream>>>(
            xa, wvT + (long)l * 1024 * 256, bv, nullptr, vT,
            256, 256, 256, 1024, (long)CT * 256, 0, (long)CT * CT,
            (long)l * 1024, 1.0f, flagp);
        // 3) Wo^T -> wscr (per-layer, 0.5 MB scratch)
        tconv_kernel<<<dim3(8, 32, 1), 256, 0, stream>>>(
            Wo, wscr, 1024, 256, 0, 0, (long)l * 1024 * 256, flagp);
        // 4) flash attention (512 blocks, KV-split x2; qk read-only)
        flash_attn<<<512, 256, 0, stream>>>(qk, vT, op0, op1, ml);
        // 5) O projection with fused partial-combine A-staging -> fp32 pgem
        mgemm64s<1><<<dim3(4, 64, 2), 256, 0, stream>>>(
            op0, op1, ml, wscr, pgem, 512, 1024, 1024);
        // 6) xa = LN(pgem0+pgem1 + bo + xa)
        ln_p<<<NROW, 256, 0, stream>>>(pgem, bo, (long)l * 256, xa,
                                       ln1s, ln1b, xa, (long)l * 256, flagp);
        // 7) h = relu(xa @ w1T^T + b1)
        mgemm<1, 1><<<dim3(8, 32, 1), 256, 0, stream>>>(
            xa, w1T + (long)l * 1024 * 256, b1, nullptr, h,
            256, 256, 256, 1024, 0, 0, 0, (long)l * 1024, 1.0f, flagp);
        // 8) W2^T -> wscr
        tconv_kernel<<<dim3(8, 32, 1), 256, 0, stream>>>(
            W2, wscr, 1024, 256, 0, 0, (long)l * 1024 * 256, flagp);
        // 9) MLP2 -> fp32 pgem
        mgemm64s<0><<<dim3(4, 64, 2), 256, 0, stream>>>(
            h, nullptr, nullptr, wscr, pgem, 512, 1024, 1024);
        // 10) xa = LN(pgem0+pgem1 + b2 + xa)
        ln_p<<<NROW, 256, 0, stream>>>(pgem, b2, (long)l * 256, xa,
                                       ln2s, ln2b, xa, (long)l * 256, flagp);
    }

    out_write<<<(NROW * CD) / 1024, 256, 0, stream>>>(xa, d_out, flagp);
}